// Round 10
// baseline (463.626 us; speedup 1.0000x reference)
//
#include <hip/hip_runtime.h>
#include <stdint.h>

// Problem constants (B=4, S=4096 -> T=16384 tokens; D=512, F=2048, E=8, top_k=2)
#define T_TOK 16384
#define D_DIM 512
#define F_DIM 2048
#define E_NUM 8
#define MAXR  34816   // 2*T + E*256 (experts padded to 256 rows)

typedef __bf16 bf16x8 __attribute__((ext_vector_type(8)));
typedef float  f32x4  __attribute__((ext_vector_type(4)));

__device__ __forceinline__ unsigned short f2b(float f) {
  union { float f; unsigned u; } a; a.f = f;
  unsigned u = a.u;
  u = u + 0x7fffu + ((u >> 16) & 1u);   // RNE
  return (unsigned short)(u >> 16);
}
__device__ __forceinline__ float b2f(unsigned short h) {
  union { unsigned u; float f; } a; a.u = ((unsigned)h) << 16;
  return a.f;
}
__device__ __forceinline__ void load_lds16(const void* g, void* l) {
  __builtin_amdgcn_global_load_lds(
      (const __attribute__((address_space(1))) void*)g,
      (__attribute__((address_space(3))) void*)l, 16, 0, 0);
}

#define CSTRIDE 16
#define BAR() __builtin_amdgcn_s_barrier()
#define SP1() __builtin_amdgcn_s_setprio(1)
#define SP0() __builtin_amdgcn_s_setprio(0)
#define VMC2() do { asm volatile("s_waitcnt vmcnt(2)" ::: "memory"); \
                    __builtin_amdgcn_sched_barrier(0); } while (0)
// drain in-flight ds_reads before a barrier whose successor overwrites their source
#define LGKM0() do { asm volatile("s_waitcnt lgkmcnt(0)" ::: "memory"); \
                     __builtin_amdgcn_sched_barrier(0); } while (0)

// ---------------- prelude: weight cvt (blocks 0..24575) + router/x-cvt ----------------
__global__ __launch_bounds__(256) void prelude_kernel(
    const float* __restrict__ x, const float* __restrict__ gw,
    const float* __restrict__ w1, const float* __restrict__ w3,
    const float* __restrict__ w2,
    int* __restrict__ sel, float* __restrict__ rw, unsigned short* __restrict__ xb,
    unsigned short* __restrict__ w1b, unsigned short* __restrict__ w3b,
    unsigned short* __restrict__ w2b)
{
  int b = blockIdx.x;
  if (b < 24576) {
    int seg = b >> 13;
    int i = (b & 8191) * 256 + threadIdx.x;
    const float* s = seg == 0 ? w1 : seg == 1 ? w3 : w2;
    unsigned short* d = seg == 0 ? w1b : seg == 1 ? w3b : w2b;
    float4 v = ((const float4*)s)[i];
    ushort4 o;
    o.x = f2b(v.x); o.y = f2b(v.y); o.z = f2b(v.z); o.w = f2b(v.w);
    ((ushort4*)d)[i] = o;
    return;
  }
  int lane = threadIdx.x & 63;
  int wid  = threadIdx.x >> 6;
  int t = (b - 24576) * 4 + wid;
  const float4* xp = (const float4*)(x + (size_t)t * D_DIM + lane * 8);
  float4 a0 = xp[0], a1 = xp[1];
  ushort4 o0, o1;
  o0.x = f2b(a0.x); o0.y = f2b(a0.y); o0.z = f2b(a0.z); o0.w = f2b(a0.w);
  o1.x = f2b(a1.x); o1.y = f2b(a1.y); o1.z = f2b(a1.z); o1.w = f2b(a1.w);
  ushort4* xbp = (ushort4*)(xb + (size_t)t * D_DIM + lane * 8);
  xbp[0] = o0; xbp[1] = o1;

  float lg[E_NUM];
#pragma unroll
  for (int e = 0; e < E_NUM; ++e) {
    const float4* gp = (const float4*)(gw + (size_t)e * D_DIM + lane * 8);
    float4 g0 = gp[0], g1 = gp[1];
    float s = a0.x*g0.x + a0.y*g0.y + a0.z*g0.z + a0.w*g0.w
            + a1.x*g1.x + a1.y*g1.y + a1.z*g1.z + a1.w*g1.w;
#pragma unroll
    for (int off = 32; off; off >>= 1) s += __shfl_xor(s, off);
    lg[e] = s;
  }
  if (lane == 0) {
    int i0 = 0; float m0 = lg[0];
#pragma unroll
    for (int e = 1; e < E_NUM; ++e) if (lg[e] > m0) { m0 = lg[e]; i0 = e; }
    int i1 = -1; float m1 = -1e30f;
#pragma unroll
    for (int e = 0; e < E_NUM; ++e) if (e != i0 && lg[e] > m1) { m1 = lg[e]; i1 = e; }
    float w0 = 1.0f / (1.0f + expf(m1 - m0));
    sel[2*t] = i0; sel[2*t+1] = i1;
    rw[2*t] = w0;  rw[2*t+1] = 1.0f - w0;
  }
}

// ---------------- hist ----------------
__global__ __launch_bounds__(256) void hist_kernel(
    const int* __restrict__ sel, int* __restrict__ counts)
{
  __shared__ int h[E_NUM];
  if (threadIdx.x < E_NUM) h[threadIdx.x] = 0;
  __syncthreads();
  int t = blockIdx.x * 256 + threadIdx.x;
  atomicAdd(&h[sel[2*t]], 1);
  atomicAdd(&h[sel[2*t+1]], 1);
  __syncthreads();
  if (threadIdx.x < E_NUM) atomicAdd(&counts[threadIdx.x * CSTRIDE], h[threadIdx.x]);
}

// ---------------- scanpad: per-expert offsets + pad fill (merged) ----------------
__global__ __launch_bounds__(256) void scanpad_kernel(
    const int* __restrict__ counts, int* __restrict__ offs, int* __restrict__ padTot,
    int* __restrict__ ptok, float* __restrict__ pw, int* __restrict__ pexp)
{
  int e = blockIdx.x;
  int o = 0, c_e = 0, tot = 0;
  for (int k = 0; k < E_NUM; ++k) {
    int c = counts[k * CSTRIDE];
    int padded = (c + 255) & ~255;
    if (k < e) o += padded;
    if (k == e) c_e = c;
    tot += padded;
  }
  if (threadIdx.x == 0) {
    offs[e] = o;
    if (e == 0) *padTot = tot;
  }
  int padded_e = (c_e + 255) & ~255;
  for (int i = c_e + threadIdx.x; i < padded_e; i += 256) {
    ptok[o+i] = 0; pw[o+i] = 0.0f; pexp[o+i] = e;
  }
}

// ---------------- assign: hierarchical ----------------
__global__ __launch_bounds__(256) void assign_kernel(
    const int* __restrict__ sel, const float* __restrict__ rw,
    const int* __restrict__ offs, int* __restrict__ cursor,
    int* __restrict__ ptok, float* __restrict__ pw, int* __restrict__ pexp,
    int* __restrict__ t2s)
{
  __shared__ int lcnt[E_NUM];
  __shared__ int base[E_NUM];
  if (threadIdx.x < E_NUM) lcnt[threadIdx.x] = 0;
  __syncthreads();
  int t = blockIdx.x * 256 + threadIdx.x;
  int e[2], rank[2];
  float w[2];
#pragma unroll
  for (int k = 0; k < 2; ++k) {
    e[k] = sel[2*t+k];
    w[k] = rw[2*t+k];
    rank[k] = atomicAdd(&lcnt[e[k]], 1);
  }
  __syncthreads();
  if (threadIdx.x < E_NUM)
    base[threadIdx.x] = atomicAdd(&cursor[threadIdx.x * CSTRIDE], lcnt[threadIdx.x]);
  __syncthreads();
#pragma unroll
  for (int k = 0; k < 2; ++k) {
    int slot = offs[e[k]] + base[e[k]] + rank[k];
    ptok[slot] = t; pw[slot] = w[k]; pexp[slot] = e[k];
    t2s[2*t+k] = slot;
  }
}

// Swizzle (HW-verified R3, conflicts=0): source chunk ((tid&7)^((tid>>3)&7))*8,
// LDS dest linear, read col ^= (lane&7)<<3.

// ======== pass A: 4-phase, 1024-thread H = relu(X*W1^T) .* (X*W3^T) ========
// Same 256x128 tile / 128KB LDS / BK=64 as R6 (memory behavior proven), but
// 16 waves (4M x 4N, wave tile 64x32) -> 4 waves/SIMD; acc 64 VGPR/wave;
// af re-read in P2/P4 keeps frag pressure low; LGKM0 guards the same-buffer
// A-restage; vmcnt(2) cadence (queue-walked incl prologue + clamped tail).
__device__ __forceinline__ void stageA4(unsigned short* dst, const unsigned short* xb,
    const int* tokr, int kt, int tid, int csw) {
  int k0 = kt * 64;
#pragma unroll
  for (int h = 0; h < 2; ++h) {
    int rl = h*128 + (tid>>3);
    load_lds16(xb + (size_t)tokr[h]*D_DIM + k0 + csw, &dst[rl*64 + (tid&7)*8]);
  }
}
__device__ __forceinline__ void stageB4(unsigned short* d, const unsigned short* W,
    int f0, int kt, int tid, int csw) {
  int k0 = kt * 64;
  int rl = tid >> 3;
  load_lds16(W + (size_t)(f0+rl)*D_DIM + k0 + csw, &d[rl*64 + (tid&7)*8]);
}
__device__ __forceinline__ void readA4(bf16x8 (*af)[2], const unsigned short* buf,
    int wm, int lane, int xs) {
#pragma unroll
  for (int m = 0; m < 4; ++m)
#pragma unroll
    for (int s = 0; s < 2; ++s)
      af[m][s] = *(const bf16x8*)&buf[(wm*64 + m*16 + (lane&15))*64 + ((s*32 + ((lane>>4)<<3)) ^ xs)];
}
__device__ __forceinline__ void readB4(bf16x8 (*bf)[2], const unsigned short* buf,
    int wn, int lane, int xs) {
#pragma unroll
  for (int n = 0; n < 2; ++n)
#pragma unroll
    for (int s = 0; s < 2; ++s)
      bf[n][s] = *(const bf16x8*)&buf[(wn*32 + n*16 + (lane&15))*64 + ((s*32 + ((lane>>4)<<3)) ^ xs)];
}
__device__ __forceinline__ void mfma16(f32x4 (*acc)[2], const bf16x8 (*af)[2], const bf16x8 (*bf)[2]) {
#pragma unroll
  for (int m = 0; m < 4; ++m)
#pragma unroll
    for (int n = 0; n < 2; ++n)
#pragma unroll
      for (int s = 0; s < 2; ++s)
        acc[m][n] = __builtin_amdgcn_mfma_f32_16x16x32_bf16(af[m][s], bf[n][s], acc[m][n], 0, 0, 0);
}

__global__ __launch_bounds__(1024) void ffn_h4_kernel(
    const unsigned short* __restrict__ xb, const unsigned short* __restrict__ w1b,
    const unsigned short* __restrict__ w3b, const int* __restrict__ ptok,
    const int* __restrict__ pexp, const int* __restrict__ padTot,
    unsigned short* __restrict__ H)
{
  __shared__ unsigned short As0[256*64], As1[256*64];    // 64KB
  __shared__ unsigned short B1s0[128*64], B1s1[128*64];  // 32KB
  __shared__ unsigned short B3s0[128*64], B3s1[128*64];  // 32KB
  int tm = blockIdx.x >> 4;
  int tn = blockIdx.x & 15;
  int row0 = tm * 256;
  if (row0 >= *padTot) return;
  int e  = pexp[row0];
  int f0 = tn * 128;
  const unsigned short* W1 = w1b + (size_t)e * F_DIM * D_DIM;
  const unsigned short* W3 = w3b + (size_t)e * F_DIM * D_DIM;
  int tid  = threadIdx.x;           // 0..1023
  int lane = tid & 63;
  int wid  = tid >> 6;              // 0..15
  int wm = wid >> 2, wn = wid & 3;  // 4M x 4N
  int xs  = (lane & 7) << 3;
  int csw = ((tid & 7) ^ ((tid >> 3) & 7)) * 8;

  int tokr[2];
#pragma unroll
  for (int h = 0; h < 2; ++h) tokr[h] = ptok[row0 + h*128 + (tid>>3)];

  f32x4 acc1[4][2] = {};
  f32x4 acc3[4][2] = {};
  bf16x8 af[4][2], b1f[2][2], b3f[2][2];

  // prologue: A(0)[2] B1(0)[1] B3(0)[1] A(1)[2]; vmcnt(2) leaves A(1) in flight
  stageA4(As0, xb, tokr, 0, tid, csw);
  stageB4(B1s0, W1, f0, 0, tid, csw);
  stageB4(B3s0, W3, f0, 0, tid, csw);
  stageA4(As1, xb, tokr, 1, tid, csw);
  VMC2();
  BAR();

  for (int i = 0; i < 4; ++i) {
    int k1 = 2*i + 1;
    int k2 = (2*i + 2 < 8) ? 2*i + 2 : 7;
    int k3 = (2*i + 3 < 8) ? 2*i + 3 : 7;
    // P1: read kt(buf0) A+B1; stage B1,B3(kt+1)->buf1; MFMA acc1
    readA4(af, As0, wm, lane, xs);
    readB4(b1f, B1s0, wn, lane, xs);
    stageB4(B1s1, W1, f0, k1, tid, csw);
    stageB4(B3s1, W3, f0, k1, tid, csw);
    BAR(); mfma16(acc1, af, b1f); BAR();
    // P2: read B3 + re-read A; drain reads; restage A(kt+2)->buf0; MFMA acc3; vmcnt(2)
    readB4(b3f, B3s0, wn, lane, xs);
    readA4(af, As0, wm, lane, xs);
    LGKM0();
    BAR();
    stageA4(As0, xb, tokr, k2, tid, csw);
    mfma16(acc3, af, b3f);
    VMC2();
    BAR();
    // P3: read kt+1(buf1) A+B1; stage B1,B3(kt+2)->buf0; MFMA acc1
    readA4(af, As1, wm, lane, xs);
    readB4(b1f, B1s1, wn, lane, xs);
    stageB4(B1s0, W1, f0, k2, tid, csw);
    stageB4(B3s0, W3, f0, k2, tid, csw);
    BAR(); mfma16(acc1, af, b1f); BAR();
    // P4: read B3 + re-read A; drain; restage A(kt+3)->buf1; MFMA acc3; vmcnt(2)
    readB4(b3f, B3s1, wn, lane, xs);
    readA4(af, As1, wm, lane, xs);
    LGKM0();
    BAR();
    stageA4(As1, xb, tokr, k3, tid, csw);
    mfma16(acc3, af, b3f);
    VMC2();
    BAR();
  }

#pragma unroll
  for (int m = 0; m < 4; ++m) {
    int rbase = row0 + wm*64 + m*16 + (lane>>4)*4;
#pragma unroll
    for (int n = 0; n < 2; ++n) {
      int col = f0 + wn*32 + n*16 + (lane & 15);
#pragma unroll
      for (int j = 0; j < 4; ++j) {
        float h = fmaxf(acc1[m][n][j], 0.0f) * acc3[m][n][j];
        H[(size_t)(rbase + j) * F_DIM + col] = f2b(h);
      }
    }
  }
}

// ======== pass B: 8-phase contrib = (H * W2^T) * row_weight (unchanged, verified) ========
__device__ __forceinline__ void readA_O(bf16x8 (*af)[2], const unsigned short* buf,
    int wm, int lane, int xs) {
#pragma unroll
  for (int m = 0; m < 4; ++m)
#pragma unroll
    for (int s = 0; s < 2; ++s)
      af[m][s] = *(const bf16x8*)&buf[(wm*64 + m*16 + (lane&15))*64 + ((s*32 + ((lane>>4)<<3)) ^ xs)];
}
__device__ __forceinline__ void readB_O(bf16x8* bf, const unsigned short* buf,
    int wn, int lane, int xs) {
#pragma unroll
  for (int s = 0; s < 2; ++s)
    bf[s] = *(const bf16x8*)&buf[(wn*16 + (lane&15))*64 + ((s*32 + ((lane>>4)<<3)) ^ xs)];
}
__device__ __forceinline__ void mfmaO(f32x4* acc, const bf16x8 (*af)[2], const bf16x8* bf) {
  SP1();
#pragma unroll
  for (int m = 0; m < 4; ++m)
#pragma unroll
    for (int s = 0; s < 2; ++s)
      acc[m] = __builtin_amdgcn_mfma_f32_16x16x32_bf16(af[m][s], bf[s], acc[m], 0, 0, 0);
  SP0();
}
__device__ __forceinline__ void stageA_O(unsigned short* dst, const unsigned short* H,
    int row0, int kt, int tid, int csw) {
  int k0 = kt * 64;
#pragma unroll
  for (int r = 0; r < 2; ++r) {
    int rl = r*64 + (tid>>3);
    load_lds16(H + (size_t)(row0+rl)*F_DIM + k0 + csw, &dst[rl*64 + (tid&7)*8]);
  }
}
__device__ __forceinline__ void stageB_O(unsigned short* d1, unsigned short* d3,
    const unsigned short* W2, int d0, int kt, int tid, int csw) {
  int k0 = kt * 64;
  int rl = tid >> 3;
  load_lds16(W2 + (size_t)(d0+rl)*F_DIM + k0 + csw, &d1[rl*64 + (tid&7)*8]);
  load_lds16(W2 + (size_t)(d0+64+rl)*F_DIM + k0 + csw, &d3[rl*64 + (tid&7)*8]);
}

__global__ __launch_bounds__(512, 4) void ffn_out8_kernel(
    const unsigned short* __restrict__ H, const unsigned short* __restrict__ w2b,
    const int* __restrict__ pexp, const float* __restrict__ pw,
    const int* __restrict__ padTot, unsigned short* __restrict__ contrib)
{
  __shared__ unsigned short As0[128*64], As1[128*64];    // 32KB
  __shared__ unsigned short B1s0[64*64], B1s1[64*64];    // 16KB
  __shared__ unsigned short B3s0[64*64], B3s1[64*64];    // 16KB
  int wgid = (blockIdx.x & 7) * 136 + (blockIdx.x >> 3);
  int tm = wgid >> 2;
  int tn = wgid & 3;
  int row0 = tm * 128;
  if (row0 >= *padTot) return;
  int e  = pexp[row0];
  int d0 = tn * 128;
  const unsigned short* W2 = w2b + (size_t)e * D_DIM * F_DIM;
  int tid  = threadIdx.x;
  int lane = tid & 63;
  int wid  = tid >> 6;
  int wm = wid >> 2, wn = wid & 3;
  int xs  = (lane & 7) << 3;
  int csw = ((tid & 7) ^ ((tid >> 3) & 7)) * 8;

  f32x4 acc1[4] = {};
  f32x4 acc3[4] = {};
  bf16x8 af[4][2], b1f[2], b3f[2];

  const int NK = F_DIM / 64;   // 32
  stageA_O(As0, H, row0, 0, tid, csw);
  stageB_O(B1s0, B3s0, W2, d0, 0, tid, csw);
  stageA_O(As1, H, row0, 1, tid, csw);
  VMC2();
  BAR();

  for (int i = 0; i < NK/2; ++i) {
    int k1 = 2*i + 1;
    int k2 = (2*i + 2 < NK) ? 2*i + 2 : NK - 1;
    int k3 = (2*i + 3 < NK) ? 2*i + 3 : NK - 1;
    readA_O(af, As0, wm, lane, xs);
    readB_O(b1f, B1s0, wn, lane, xs);
    readB_O(b3f, B3s0, wn, lane, xs);
    stageB_O(B1s1, B3s1, W2, d0, k1, tid, csw);
    BAR(); mfmaO(acc1, af, b1f); BAR();
    stageA_O(As0, H, row0, k2, tid, csw);
    VMC2();
    BAR(); mfmaO(acc3, af, b3f); BAR();
    readA_O(af, As1, wm, lane, xs);
    readB_O(b1f, B1s1, wn, lane, xs);
    readB_O(b3f, B3s1, wn, lane, xs);
    stageB_O(B1s0, B3s0, W2, d0, k2, tid, csw);
    BAR(); mfmaO(acc1, af, b1f); BAR();
    stageA_O(As1, H, row0, k3, tid, csw);
    VMC2();
    BAR(); mfmaO(acc3, af, b3f); BAR();
  }

#pragma unroll
  for (int m = 0; m < 4; ++m) {
    int rbase = row0 + wm*64 + m*16 + (lane>>4)*4;
    float sw[4];
#pragma unroll
    for (int j = 0; j < 4; ++j) sw[j] = pw[rbase + j];
    int colL = d0 + wn*16 + (lane & 15);
#pragma unroll
    for (int j = 0; j < 4; ++j) {
      contrib[(size_t)(rbase + j) * D_DIM + colL]      = f2b(acc1[m][j] * sw[j]);
      contrib[(size_t)(rbase + j) * D_DIM + colL + 64] = f2b(acc3[m][j] * sw[j]);
    }
  }
}

// ---------------- combine ----------------
__global__ __launch_bounds__(256) void combine_kernel(
    const unsigned short* __restrict__ contrib, const int* __restrict__ t2s,
    float* __restrict__ out)
{
  int i = blockIdx.x * 256 + threadIdx.x;
  int t = i >> 7;
  int c = (i & 127) * 4;
  int s0 = t2s[2*t], s1 = t2s[2*t+1];
  ushort4 u0 = *(const ushort4*)&contrib[(size_t)s0 * D_DIM + c];
  ushort4 u1 = *(const ushort4*)&contrib[(size_t)s1 * D_DIM + c];
  float4 o;
  o.x = b2f(u0.x) + b2f(u1.x);
  o.y = b2f(u0.y) + b2f(u1.y);
  o.z = b2f(u0.z) + b2f(u1.z);
  o.w = b2f(u0.w) + b2f(u1.w);
  *(float4*)&out[(size_t)t * D_DIM + c] = o;
}

// ---------------- workspace layout ----------------
#define OFF_SEL   ((size_t)2048)
#define OFF_RW    (OFF_SEL  + (size_t)2*T_TOK*4)
#define OFF_T2S   (OFF_RW   + (size_t)2*T_TOK*4)
#define OFF_PTOK  (OFF_T2S  + (size_t)2*T_TOK*4)
#define OFF_PW    (OFF_PTOK + (size_t)MAXR*4)
#define OFF_PEXP  (OFF_PW   + (size_t)MAXR*4)
#define OFF_XB    (OFF_PEXP + (size_t)MAXR*4)
#define OFF_W1B   (OFF_XB   + (size_t)T_TOK*D_DIM*2)
#define OFF_W3B   (OFF_W1B  + (size_t)E_NUM*F_DIM*D_DIM*2)
#define OFF_W2B   (OFF_W3B  + (size_t)E_NUM*F_DIM*D_DIM*2)
#define OFF_H     (OFF_W2B  + (size_t)E_NUM*F_DIM*D_DIM*2)
#define OFF_CONTR OFF_XB   // overlays xb+w1b (dead during pass B)

extern "C" void kernel_launch(void* const* d_in, const int* in_sizes, int n_in,
                              void* d_out, int out_size, void* d_ws, size_t ws_size,
                              hipStream_t stream) {
  const float* x  = (const float*)d_in[0];
  const float* gw = (const float*)d_in[1];
  const float* w1 = (const float*)d_in[2];
  const float* w2 = (const float*)d_in[3];
  const float* w3 = (const float*)d_in[4];
  float* out = (float*)d_out;
  char* ws = (char*)d_ws;

  int*   counts = (int*)(ws + 0);
  int*   cursor = (int*)(ws + 512);
  int*   offs   = (int*)(ws + 1024);
  int*   padTot = (int*)(ws + 1056);
  int*   sel    = (int*)(ws + OFF_SEL);
  float* rw     = (float*)(ws + OFF_RW);
  int*   t2s    = (int*)(ws + OFF_T2S);
  int*   ptok   = (int*)(ws + OFF_PTOK);
  float* pw     = (float*)(ws + OFF_PW);
  int*   pexp   = (int*)(ws + OFF_PEXP);
  unsigned short* xb      = (unsigned short*)(ws + OFF_XB);
  unsigned short* w1b     = (unsigned short*)(ws + OFF_W1B);
  unsigned short* w3b     = (unsigned short*)(ws + OFF_W3B);
  unsigned short* w2b     = (unsigned short*)(ws + OFF_W2B);
  unsigned short* Hbuf    = (unsigned short*)(ws + OFF_H);
  unsigned short* contrib = (unsigned short*)(ws + OFF_CONTR);

  hipMemsetAsync(ws, 0, 2048, stream);

  prelude_kernel<<<24576 + T_TOK/4, 256, 0, stream>>>(x, gw, w1, w3, w2,
                                                      sel, rw, xb, w1b, w3b, w2b);
  hist_kernel<<<T_TOK/256, 256, 0, stream>>>(sel, counts);
  scanpad_kernel<<<E_NUM, 256, 0, stream>>>(counts, offs, padTot, ptok, pw, pexp);
  assign_kernel<<<T_TOK/256, 256, 0, stream>>>(sel, rw, offs, cursor, ptok, pw, pexp, t2s);

  ffn_h4_kernel<<<(MAXR/256)*(F_DIM/128), 1024, 0, stream>>>(xb, w1b, w3b, ptok, pexp, padTot, Hbuf);
  ffn_out8_kernel<<<(MAXR/128)*(D_DIM/128), 512, 0, stream>>>(Hbuf, w2b, pexp, pw, padTot, contrib);
  combine_kernel<<<(T_TOK*D_DIM/4)/256, 256, 0, stream>>>(contrib, t2s, out);

  (void)in_sizes; (void)n_in; (void)out_size; (void)ws_size;
}

// Round 11
// 395.416 us; speedup vs baseline: 1.1725x; 1.1725x over previous
//
#include <hip/hip_runtime.h>
#include <stdint.h>

// Problem constants (B=4, S=4096 -> T=16384 tokens; D=512, F=2048, E=8, top_k=2)
#define T_TOK 16384
#define D_DIM 512
#define F_DIM 2048
#define E_NUM 8
#define MAXR  34816   // 2*T + E*256 (experts padded to 256 rows)

typedef __bf16 bf16x8 __attribute__((ext_vector_type(8)));
typedef float  f32x4  __attribute__((ext_vector_type(4)));

__device__ __forceinline__ unsigned short f2b(float f) {
  union { float f; unsigned u; } a; a.f = f;
  unsigned u = a.u;
  u = u + 0x7fffu + ((u >> 16) & 1u);   // RNE
  return (unsigned short)(u >> 16);
}
__device__ __forceinline__ void load_lds16(const void* g, void* l) {
  __builtin_amdgcn_global_load_lds(
      (const __attribute__((address_space(1))) void*)g,
      (__attribute__((address_space(3))) void*)l, 16, 0, 0);
}

#define CSTRIDE 16
#define BAR() __builtin_amdgcn_s_barrier()
#define SP1() __builtin_amdgcn_s_setprio(1)
#define SP0() __builtin_amdgcn_s_setprio(0)
#define VMC6() do { asm volatile("s_waitcnt vmcnt(6)" ::: "memory"); \
                    __builtin_amdgcn_sched_barrier(0); } while (0)
#define VMC2() do { asm volatile("s_waitcnt vmcnt(2)" ::: "memory"); \
                    __builtin_amdgcn_sched_barrier(0); } while (0)

// ---------------- prelude: weight cvt (blocks 0..24575) + router/x-cvt ----------------
__global__ __launch_bounds__(256) void prelude_kernel(
    const float* __restrict__ x, const float* __restrict__ gw,
    const float* __restrict__ w1, const float* __restrict__ w3,
    const float* __restrict__ w2,
    int* __restrict__ sel, float* __restrict__ rw, unsigned short* __restrict__ xb,
    unsigned short* __restrict__ w1b, unsigned short* __restrict__ w3b,
    unsigned short* __restrict__ w2b)
{
  int b = blockIdx.x;
  if (b < 24576) {
    int seg = b >> 13;
    int i = (b & 8191) * 256 + threadIdx.x;
    const float* s = seg == 0 ? w1 : seg == 1 ? w3 : w2;
    unsigned short* d = seg == 0 ? w1b : seg == 1 ? w3b : w2b;
    float4 v = ((const float4*)s)[i];
    ushort4 o;
    o.x = f2b(v.x); o.y = f2b(v.y); o.z = f2b(v.z); o.w = f2b(v.w);
    ((ushort4*)d)[i] = o;
    return;
  }
  int lane = threadIdx.x & 63;
  int wid  = threadIdx.x >> 6;
  int t = (b - 24576) * 4 + wid;
  const float4* xp = (const float4*)(x + (size_t)t * D_DIM + lane * 8);
  float4 a0 = xp[0], a1 = xp[1];
  ushort4 o0, o1;
  o0.x = f2b(a0.x); o0.y = f2b(a0.y); o0.z = f2b(a0.z); o0.w = f2b(a0.w);
  o1.x = f2b(a1.x); o1.y = f2b(a1.y); o1.z = f2b(a1.z); o1.w = f2b(a1.w);
  ushort4* xbp = (ushort4*)(xb + (size_t)t * D_DIM + lane * 8);
  xbp[0] = o0; xbp[1] = o1;

  float lg[E_NUM];
#pragma unroll
  for (int e = 0; e < E_NUM; ++e) {
    const float4* gp = (const float4*)(gw + (size_t)e * D_DIM + lane * 8);
    float4 g0 = gp[0], g1 = gp[1];
    float s = a0.x*g0.x + a0.y*g0.y + a0.z*g0.z + a0.w*g0.w
            + a1.x*g1.x + a1.y*g1.y + a1.z*g1.z + a1.w*g1.w;
#pragma unroll
    for (int off = 32; off; off >>= 1) s += __shfl_xor(s, off);
    lg[e] = s;
  }
  if (lane == 0) {
    int i0 = 0; float m0 = lg[0];
#pragma unroll
    for (int e = 1; e < E_NUM; ++e) if (lg[e] > m0) { m0 = lg[e]; i0 = e; }
    int i1 = -1; float m1 = -1e30f;
#pragma unroll
    for (int e = 0; e < E_NUM; ++e) if (e != i0 && lg[e] > m1) { m1 = lg[e]; i1 = e; }
    float w0 = 1.0f / (1.0f + expf(m1 - m0));
    sel[2*t] = i0; sel[2*t+1] = i1;
    rw[2*t] = w0;  rw[2*t+1] = 1.0f - w0;
  }
}

// ---------------- hist ----------------
__global__ __launch_bounds__(256) void hist_kernel(
    const int* __restrict__ sel, int* __restrict__ counts)
{
  __shared__ int h[E_NUM];
  if (threadIdx.x < E_NUM) h[threadIdx.x] = 0;
  __syncthreads();
  int t = blockIdx.x * 256 + threadIdx.x;
  atomicAdd(&h[sel[2*t]], 1);
  atomicAdd(&h[sel[2*t+1]], 1);
  __syncthreads();
  if (threadIdx.x < E_NUM) atomicAdd(&counts[threadIdx.x * CSTRIDE], h[threadIdx.x]);
}

// ---------------- scanpad: per-expert offsets + pad fill (merged) ----------------
__global__ __launch_bounds__(256) void scanpad_kernel(
    const int* __restrict__ counts, int* __restrict__ offs, int* __restrict__ padTot,
    int* __restrict__ ptok, float* __restrict__ pw, int* __restrict__ pexp)
{
  int e = blockIdx.x;
  int o = 0, c_e = 0, tot = 0;
  for (int k = 0; k < E_NUM; ++k) {
    int c = counts[k * CSTRIDE];
    int padded = (c + 255) & ~255;
    if (k < e) o += padded;
    if (k == e) c_e = c;
    tot += padded;
  }
  if (threadIdx.x == 0) {
    offs[e] = o;
    if (e == 0) *padTot = tot;
  }
  int padded_e = (c_e + 255) & ~255;
  for (int i = c_e + threadIdx.x; i < padded_e; i += 256) {
    ptok[o+i] = 0; pw[o+i] = 0.0f; pexp[o+i] = e;
  }
}

// ---------------- assign: hierarchical ----------------
__global__ __launch_bounds__(256) void assign_kernel(
    const int* __restrict__ sel, const float* __restrict__ rw,
    const int* __restrict__ offs, int* __restrict__ cursor,
    int* __restrict__ ptok, float* __restrict__ pw, int* __restrict__ pexp)
{
  __shared__ int lcnt[E_NUM];
  __shared__ int base[E_NUM];
  if (threadIdx.x < E_NUM) lcnt[threadIdx.x] = 0;
  __syncthreads();
  int t = blockIdx.x * 256 + threadIdx.x;
  int e[2], rank[2];
  float w[2];
#pragma unroll
  for (int k = 0; k < 2; ++k) {
    e[k] = sel[2*t+k];
    w[k] = rw[2*t+k];
    rank[k] = atomicAdd(&lcnt[e[k]], 1);
  }
  __syncthreads();
  if (threadIdx.x < E_NUM)
    base[threadIdx.x] = atomicAdd(&cursor[threadIdx.x * CSTRIDE], lcnt[threadIdx.x]);
  __syncthreads();
#pragma unroll
  for (int k = 0; k < 2; ++k) {
    int slot = offs[e[k]] + base[e[k]] + rank[k];
    ptok[slot] = t; pw[slot] = w[k]; pexp[slot] = e[k];
  }
}

// Swizzle (HW-verified R3, conflicts=0): source chunk ((tid&7)^((tid>>3)&7))*8,
// LDS dest linear, read col ^= (lane&7)<<3.

// ======== pass A: 8-phase pipelined H = relu(X*W1^T) .* (X*W3^T) ========
// R9 config EXACTLY (measured optimum of 6 variants): 256x128 tile, 8 waves,
// 1 blk/CU, NO setprio, NO XCD swizzle.
__device__ __forceinline__ void stageA8(unsigned short* dst, const unsigned short* xb,
    const int* tokr, int kt, int half, int tid, int csw) {
  int k0 = kt * 64;
#pragma unroll
  for (int r = 0; r < 2; ++r) {
    int h = half*2 + r;
    int rl = h*64 + (tid>>3);
    load_lds16(xb + (size_t)tokr[h]*D_DIM + k0 + csw, &dst[rl*64 + (tid&7)*8]);
  }
}
__device__ __forceinline__ void stageB8(unsigned short* dst, const unsigned short* W,
    int f0, int kt, int tid, int csw) {
  int k0 = kt * 64;
#pragma unroll
  for (int r = 0; r < 2; ++r) {
    int rl = r*64 + (tid>>3);
    load_lds16(W + (size_t)(f0+rl)*D_DIM + k0 + csw, &dst[rl*64 + (tid&7)*8]);
  }
}
__device__ __forceinline__ void readA8(bf16x8 (*af)[2], const unsigned short* buf,
    int wm, int lane, int xs, int mlo) {
#pragma unroll
  for (int m = 0; m < 4; ++m)
#pragma unroll
    for (int s = 0; s < 2; ++s)
      af[m][s] = *(const bf16x8*)&buf[(wm*128 + (mlo+m)*16 + (lane&15))*64 + ((s*32 + ((lane>>4)<<3)) ^ xs)];
}
__device__ __forceinline__ void readB8(bf16x8 (*bf)[2], const unsigned short* buf,
    int wn, int lane, int xs) {
#pragma unroll
  for (int n = 0; n < 2; ++n)
#pragma unroll
    for (int s = 0; s < 2; ++s)
      bf[n][s] = *(const bf16x8*)&buf[(wn*32 + n*16 + (lane&15))*64 + ((s*32 + ((lane>>4)<<3)) ^ xs)];
}
// pass A MFMA cluster: NO setprio
__device__ __forceinline__ void mfmaq(f32x4 (*acc)[2], const bf16x8 (*af)[2], const bf16x8 (*bf)[2]) {
#pragma unroll
  for (int m = 0; m < 4; ++m)
#pragma unroll
    for (int n = 0; n < 2; ++n)
#pragma unroll
      for (int s = 0; s < 2; ++s)
        acc[m][n] = __builtin_amdgcn_mfma_f32_16x16x32_bf16(af[m][s], bf[n][s], acc[m][n], 0, 0, 0);
}

__global__ __launch_bounds__(512, 2) void ffn_h8_kernel(
    const unsigned short* __restrict__ xb, const unsigned short* __restrict__ w1b,
    const unsigned short* __restrict__ w3b, const int* __restrict__ ptok,
    const int* __restrict__ pexp, const int* __restrict__ padTot,
    unsigned short* __restrict__ H)
{
  __shared__ unsigned short As0[256*64], As1[256*64];    // 64KB
  __shared__ unsigned short B1s0[128*64], B1s1[128*64];  // 32KB
  __shared__ unsigned short B3s0[128*64], B3s1[128*64];  // 32KB
  int tm = blockIdx.x >> 4;
  int tn = blockIdx.x & 15;
  int row0 = tm * 256;
  if (row0 >= *padTot) return;
  int e  = pexp[row0];
  int f0 = tn * 128;
  const unsigned short* W1 = w1b + (size_t)e * F_DIM * D_DIM;
  const unsigned short* W3 = w3b + (size_t)e * F_DIM * D_DIM;
  int tid  = threadIdx.x;
  int lane = tid & 63;
  int wid  = tid >> 6;
  int wm = wid >> 2, wn = wid & 3;
  int xs  = (lane & 7) << 3;
  int csw = ((tid & 7) ^ ((tid >> 3) & 7)) * 8;

  int tokr[4];
#pragma unroll
  for (int h = 0; h < 4; ++h) tokr[h] = ptok[row0 + h*64 + (tid>>3)];

  f32x4 acc1[8][2] = {};
  f32x4 acc3[8][2] = {};
  bf16x8 afL[4][2], afH[4][2], b1f[2][2], b3f[2][2];

  // prologue: kt0 {B1,Alo,Ahi,B3} + kt1 {B1,Alo,Ahi}
  stageB8(B1s0, W1, f0, 0, tid, csw);
  stageA8(As0, xb, tokr, 0, 0, tid, csw);
  stageA8(As0, xb, tokr, 0, 1, tid, csw);
  stageB8(B3s0, W3, f0, 0, tid, csw);
  stageB8(B1s1, W1, f0, 1, tid, csw);
  stageA8(As1, xb, tokr, 1, 0, tid, csw);
  stageA8(As1, xb, tokr, 1, 1, tid, csw);
  VMC6();
  BAR();

  for (int i = 0; i < 4; ++i) {
    int ktB = 2*i + 1;
    int s2 = (2*i + 2 < 8) ? 2*i + 2 : 6;
    int s3 = (2*i + 3 < 8) ? 2*i + 3 : 7;
    // ---- K-tile 2i from buf0 ----
    readA8(afL, As0, wm, lane, xs, 0);
    readB8(b1f, B1s0, wn, lane, xs);
    stageB8(B3s1, W3, f0, ktB, tid, csw);
    BAR(); mfmaq(&acc1[0], afL, b1f); BAR();
    readA8(afH, As0, wm, lane, xs, 4);
    stageB8(B1s0, W1, f0, s2, tid, csw);
    BAR(); mfmaq(&acc1[4], afH, b1f); BAR();
    readB8(b3f, B3s0, wn, lane, xs);
    stageA8(As0, xb, tokr, s2, 0, tid, csw);
    BAR(); mfmaq(&acc3[0], afL, b3f); BAR();
    stageA8(As0, xb, tokr, s2, 1, tid, csw);
    VMC6();
    BAR(); mfmaq(&acc3[4], afH, b3f); BAR();
    // ---- K-tile 2i+1 from buf1 ----
    readA8(afL, As1, wm, lane, xs, 0);
    readB8(b1f, B1s1, wn, lane, xs);
    stageB8(B3s0, W3, f0, s2, tid, csw);
    BAR(); mfmaq(&acc1[0], afL, b1f); BAR();
    readA8(afH, As1, wm, lane, xs, 4);
    stageB8(B1s1, W1, f0, s3, tid, csw);
    BAR(); mfmaq(&acc1[4], afH, b1f); BAR();
    readB8(b3f, B3s1, wn, lane, xs);
    stageA8(As1, xb, tokr, s3, 0, tid, csw);
    BAR(); mfmaq(&acc3[0], afL, b3f); BAR();
    stageA8(As1, xb, tokr, s3, 1, tid, csw);
    VMC6();
    BAR(); mfmaq(&acc3[4], afH, b3f); BAR();
  }

#pragma unroll
  for (int mi = 0; mi < 8; ++mi) {
    int rbase = row0 + wm*128 + mi*16 + (lane>>4)*4;
#pragma unroll
    for (int ni = 0; ni < 2; ++ni) {
      int col = f0 + wn*32 + ni*16 + (lane & 15);
#pragma unroll
      for (int j = 0; j < 4; ++j) {
        float h = fmaxf(acc1[mi][ni][j], 0.0f) * acc3[mi][ni][j];
        H[(size_t)(rbase + j) * F_DIM + col] = f2b(h);
      }
    }
  }
}

// ======== pass B: 8-phase (H * W2^T) * row_weight, direct f32 atomicAdd to out ========
// Each out element gets exactly 2 nonzero adds (+ exact-zero pad adds) -> f32 add
// commutativity makes the result replay-deterministic. out zeroed per call.
__device__ __forceinline__ void readA_O(bf16x8 (*af)[2], const unsigned short* buf,
    int wm, int lane, int xs) {
#pragma unroll
  for (int m = 0; m < 4; ++m)
#pragma unroll
    for (int s = 0; s < 2; ++s)
      af[m][s] = *(const bf16x8*)&buf[(wm*64 + m*16 + (lane&15))*64 + ((s*32 + ((lane>>4)<<3)) ^ xs)];
}
__device__ __forceinline__ void readB_O(bf16x8* bf, const unsigned short* buf,
    int wn, int lane, int xs) {
#pragma unroll
  for (int s = 0; s < 2; ++s)
    bf[s] = *(const bf16x8*)&buf[(wn*16 + (lane&15))*64 + ((s*32 + ((lane>>4)<<3)) ^ xs)];
}
__device__ __forceinline__ void mfmaO(f32x4* acc, const bf16x8 (*af)[2], const bf16x8* bf) {
  SP1();
#pragma unroll
  for (int m = 0; m < 4; ++m)
#pragma unroll
    for (int s = 0; s < 2; ++s)
      acc[m] = __builtin_amdgcn_mfma_f32_16x16x32_bf16(af[m][s], bf[s], acc[m], 0, 0, 0);
  SP0();
}
__device__ __forceinline__ void stageA_O(unsigned short* dst, const unsigned short* H,
    int row0, int kt, int tid, int csw) {
  int k0 = kt * 64;
#pragma unroll
  for (int r = 0; r < 2; ++r) {
    int rl = r*64 + (tid>>3);
    load_lds16(H + (size_t)(row0+rl)*F_DIM + k0 + csw, &dst[rl*64 + (tid&7)*8]);
  }
}
__device__ __forceinline__ void stageB_O(unsigned short* d1, unsigned short* d3,
    const unsigned short* W2, int d0, int kt, int tid, int csw) {
  int k0 = kt * 64;
  int rl = tid >> 3;
  load_lds16(W2 + (size_t)(d0+rl)*F_DIM + k0 + csw, &d1[rl*64 + (tid&7)*8]);
  load_lds16(W2 + (size_t)(d0+64+rl)*F_DIM + k0 + csw, &d3[rl*64 + (tid&7)*8]);
}

__global__ __launch_bounds__(512, 4) void ffn_out8_kernel(
    const unsigned short* __restrict__ H, const unsigned short* __restrict__ w2b,
    const int* __restrict__ pexp, const float* __restrict__ pw,
    const int* __restrict__ ptok, const int* __restrict__ padTot,
    float* __restrict__ out)
{
  __shared__ unsigned short As0[128*64], As1[128*64];    // 32KB
  __shared__ unsigned short B1s0[64*64], B1s1[64*64];    // 16KB
  __shared__ unsigned short B3s0[64*64], B3s1[64*64];    // 16KB
  int wgid = (blockIdx.x & 7) * 136 + (blockIdx.x >> 3);
  int tm = wgid >> 2;
  int tn = wgid & 3;
  int row0 = tm * 128;
  if (row0 >= *padTot) return;
  int e  = pexp[row0];
  int d0 = tn * 128;
  const unsigned short* W2 = w2b + (size_t)e * D_DIM * F_DIM;
  int tid  = threadIdx.x;
  int lane = tid & 63;
  int wid  = tid >> 6;
  int wm = wid >> 2, wn = wid & 3;
  int xs  = (lane & 7) << 3;
  int csw = ((tid & 7) ^ ((tid >> 3) & 7)) * 8;

  f32x4 acc1[4] = {};
  f32x4 acc3[4] = {};
  bf16x8 af[4][2], b1f[2], b3f[2];

  const int NK = F_DIM / 64;   // 32
  stageA_O(As0, H, row0, 0, tid, csw);
  stageB_O(B1s0, B3s0, W2, d0, 0, tid, csw);
  stageA_O(As1, H, row0, 1, tid, csw);
  VMC2();
  BAR();

  for (int i = 0; i < NK/2; ++i) {
    int k1 = 2*i + 1;
    int k2 = (2*i + 2 < NK) ? 2*i + 2 : NK - 1;
    int k3 = (2*i + 3 < NK) ? 2*i + 3 : NK - 1;
    readA_O(af, As0, wm, lane, xs);
    readB_O(b1f, B1s0, wn, lane, xs);
    readB_O(b3f, B3s0, wn, lane, xs);
    stageB_O(B1s1, B3s1, W2, d0, k1, tid, csw);
    BAR(); mfmaO(acc1, af, b1f); BAR();
    stageA_O(As0, H, row0, k2, tid, csw);
    VMC2();
    BAR(); mfmaO(acc3, af, b3f); BAR();
    readA_O(af, As1, wm, lane, xs);
    readB_O(b1f, B1s1, wn, lane, xs);
    readB_O(b3f, B3s1, wn, lane, xs);
    stageB_O(B1s0, B3s0, W2, d0, k2, tid, csw);
    BAR(); mfmaO(acc1, af, b1f); BAR();
    stageA_O(As1, H, row0, k3, tid, csw);
    VMC2();
    BAR(); mfmaO(acc3, af, b3f); BAR();
  }

#pragma unroll
  for (int m = 0; m < 4; ++m) {
    int rbase = row0 + wm*64 + m*16 + (lane>>4)*4;
    int colL = d0 + wn*16 + (lane & 15);
#pragma unroll
    for (int j = 0; j < 4; ++j) {
      float sw = pw[rbase + j];
      int   tk = ptok[rbase + j];
      atomicAdd(&out[(size_t)tk * D_DIM + colL],      acc1[m][j] * sw);
      atomicAdd(&out[(size_t)tk * D_DIM + colL + 64], acc3[m][j] * sw);
    }
  }
}

// ---------------- workspace layout ----------------
#define OFF_SEL   ((size_t)2048)
#define OFF_RW    (OFF_SEL  + (size_t)2*T_TOK*4)
#define OFF_PTOK  (OFF_RW   + (size_t)2*T_TOK*4)
#define OFF_PW    (OFF_PTOK + (size_t)MAXR*4)
#define OFF_PEXP  (OFF_PW   + (size_t)MAXR*4)
#define OFF_XB    (OFF_PEXP + (size_t)MAXR*4)
#define OFF_W1B   (OFF_XB   + (size_t)T_TOK*D_DIM*2)
#define OFF_W3B   (OFF_W1B  + (size_t)E_NUM*F_DIM*D_DIM*2)
#define OFF_W2B   (OFF_W3B  + (size_t)E_NUM*F_DIM*D_DIM*2)
#define OFF_H     (OFF_W2B  + (size_t)E_NUM*F_DIM*D_DIM*2)

extern "C" void kernel_launch(void* const* d_in, const int* in_sizes, int n_in,
                              void* d_out, int out_size, void* d_ws, size_t ws_size,
                              hipStream_t stream) {
  const float* x  = (const float*)d_in[0];
  const float* gw = (const float*)d_in[1];
  const float* w1 = (const float*)d_in[2];
  const float* w2 = (const float*)d_in[3];
  const float* w3 = (const float*)d_in[4];
  float* out = (float*)d_out;
  char* ws = (char*)d_ws;

  int*   counts = (int*)(ws + 0);
  int*   cursor = (int*)(ws + 512);
  int*   offs   = (int*)(ws + 1024);
  int*   padTot = (int*)(ws + 1056);
  int*   sel    = (int*)(ws + OFF_SEL);
  float* rw     = (float*)(ws + OFF_RW);
  int*   ptok   = (int*)(ws + OFF_PTOK);
  float* pw     = (float*)(ws + OFF_PW);
  int*   pexp   = (int*)(ws + OFF_PEXP);
  unsigned short* xb      = (unsigned short*)(ws + OFF_XB);
  unsigned short* w1b     = (unsigned short*)(ws + OFF_W1B);
  unsigned short* w3b     = (unsigned short*)(ws + OFF_W3B);
  unsigned short* w2b     = (unsigned short*)(ws + OFF_W2B);
  unsigned short* Hbuf    = (unsigned short*)(ws + OFF_H);

  hipMemsetAsync(ws, 0, 2048, stream);
  hipMemsetAsync(out, 0, (size_t)T_TOK * D_DIM * 4, stream);  // atomic-add target

  prelude_kernel<<<24576 + T_TOK/4, 256, 0, stream>>>(x, gw, w1, w3, w2,
                                                      sel, rw, xb, w1b, w3b, w2b);
  hist_kernel<<<T_TOK/256, 256, 0, stream>>>(sel, counts);
  scanpad_kernel<<<E_NUM, 256, 0, stream>>>(counts, offs, padTot, ptok, pw, pexp);
  assign_kernel<<<T_TOK/256, 256, 0, stream>>>(sel, rw, offs, cursor, ptok, pw, pexp);

  ffn_h8_kernel<<<(MAXR/256)*(F_DIM/128), 512, 0, stream>>>(xb, w1b, w3b, ptok, pexp, padTot, Hbuf);
  ffn_out8_kernel<<<(MAXR/128)*(D_DIM/128), 512, 0, stream>>>(Hbuf, w2b, pexp, pw, ptok, padTot, out);

  (void)in_sizes; (void)n_in; (void)out_size; (void)ws_size;
}

// Round 12
// 311.967 us; speedup vs baseline: 1.4861x; 1.2675x over previous
//
#include <hip/hip_runtime.h>
#include <stdint.h>

// Problem constants (B=4, S=4096 -> T=16384 tokens; D=512, F=2048, E=8, top_k=2)
#define T_TOK 16384
#define D_DIM 512
#define F_DIM 2048
#define E_NUM 8
#define MAXR  34816   // 2*T + E*256 (experts padded to 256 rows)

typedef __bf16 bf16x8 __attribute__((ext_vector_type(8)));
typedef float  f32x4  __attribute__((ext_vector_type(4)));

__device__ __forceinline__ unsigned short f2b(float f) {
  union { float f; unsigned u; } a; a.f = f;
  unsigned u = a.u;
  u = u + 0x7fffu + ((u >> 16) & 1u);   // RNE
  return (unsigned short)(u >> 16);
}
__device__ __forceinline__ float b2f(unsigned short h) {
  union { unsigned u; float f; } a; a.u = ((unsigned)h) << 16;
  return a.f;
}
__device__ __forceinline__ void load_lds16(const void* g, void* l) {
  __builtin_amdgcn_global_load_lds(
      (const __attribute__((address_space(1))) void*)g,
      (__attribute__((address_space(3))) void*)l, 16, 0, 0);
}

#define CSTRIDE 16
#define BAR() __builtin_amdgcn_s_barrier()
#define SP1() __builtin_amdgcn_s_setprio(1)
#define SP0() __builtin_amdgcn_s_setprio(0)
#define VMC6() do { asm volatile("s_waitcnt vmcnt(6)" ::: "memory"); \
                    __builtin_amdgcn_sched_barrier(0); } while (0)
#define VMC2() do { asm volatile("s_waitcnt vmcnt(2)" ::: "memory"); \
                    __builtin_amdgcn_sched_barrier(0); } while (0)

// ---------------- prelude: weight cvt (blocks 0..24575) + router/x-cvt ----------------
__global__ __launch_bounds__(256) void prelude_kernel(
    const float* __restrict__ x, const float* __restrict__ gw,
    const float* __restrict__ w1, const float* __restrict__ w3,
    const float* __restrict__ w2,
    int* __restrict__ sel, float* __restrict__ rw, unsigned short* __restrict__ xb,
    unsigned short* __restrict__ w1b, unsigned short* __restrict__ w3b,
    unsigned short* __restrict__ w2b)
{
  int b = blockIdx.x;
  if (b < 24576) {
    int seg = b >> 13;
    int i = (b & 8191) * 256 + threadIdx.x;
    const float* s = seg == 0 ? w1 : seg == 1 ? w3 : w2;
    unsigned short* d = seg == 0 ? w1b : seg == 1 ? w3b : w2b;
    float4 v = ((const float4*)s)[i];
    ushort4 o;
    o.x = f2b(v.x); o.y = f2b(v.y); o.z = f2b(v.z); o.w = f2b(v.w);
    ((ushort4*)d)[i] = o;
    return;
  }
  int lane = threadIdx.x & 63;
  int wid  = threadIdx.x >> 6;
  int t = (b - 24576) * 4 + wid;
  const float4* xp = (const float4*)(x + (size_t)t * D_DIM + lane * 8);
  float4 a0 = xp[0], a1 = xp[1];
  ushort4 o0, o1;
  o0.x = f2b(a0.x); o0.y = f2b(a0.y); o0.z = f2b(a0.z); o0.w = f2b(a0.w);
  o1.x = f2b(a1.x); o1.y = f2b(a1.y); o1.z = f2b(a1.z); o1.w = f2b(a1.w);
  ushort4* xbp = (ushort4*)(xb + (size_t)t * D_DIM + lane * 8);
  xbp[0] = o0; xbp[1] = o1;

  float lg[E_NUM];
#pragma unroll
  for (int e = 0; e < E_NUM; ++e) {
    const float4* gp = (const float4*)(gw + (size_t)e * D_DIM + lane * 8);
    float4 g0 = gp[0], g1 = gp[1];
    float s = a0.x*g0.x + a0.y*g0.y + a0.z*g0.z + a0.w*g0.w
            + a1.x*g1.x + a1.y*g1.y + a1.z*g1.z + a1.w*g1.w;
#pragma unroll
    for (int off = 32; off; off >>= 1) s += __shfl_xor(s, off);
    lg[e] = s;
  }
  if (lane == 0) {
    int i0 = 0; float m0 = lg[0];
#pragma unroll
    for (int e = 1; e < E_NUM; ++e) if (lg[e] > m0) { m0 = lg[e]; i0 = e; }
    int i1 = -1; float m1 = -1e30f;
#pragma unroll
    for (int e = 0; e < E_NUM; ++e) if (e != i0 && lg[e] > m1) { m1 = lg[e]; i1 = e; }
    float w0 = 1.0f / (1.0f + expf(m1 - m0));
    sel[2*t] = i0; sel[2*t+1] = i1;
    rw[2*t] = w0;  rw[2*t+1] = 1.0f - w0;
  }
}

// ---------------- hist ----------------
__global__ __launch_bounds__(256) void hist_kernel(
    const int* __restrict__ sel, int* __restrict__ counts)
{
  __shared__ int h[E_NUM];
  if (threadIdx.x < E_NUM) h[threadIdx.x] = 0;
  __syncthreads();
  int t = blockIdx.x * 256 + threadIdx.x;
  atomicAdd(&h[sel[2*t]], 1);
  atomicAdd(&h[sel[2*t+1]], 1);
  __syncthreads();
  if (threadIdx.x < E_NUM) atomicAdd(&counts[threadIdx.x * CSTRIDE], h[threadIdx.x]);
}

// ---------------- assignpad: offs recomputed per-block + pad fill + scatter ----------------
// 64 blocks x 256 threads. Every block derives offs[] locally from counts (8 loads).
// Blocks 0..7 additionally pad-fill expert blockIdx; block 0 writes padTot.
// All slot writes disjoint -> deterministic regardless of block order.
__global__ __launch_bounds__(256) void assignpad_kernel(
    const int* __restrict__ sel, const float* __restrict__ rw,
    const int* __restrict__ counts, int* __restrict__ cursor, int* __restrict__ padTot,
    int* __restrict__ ptok, float* __restrict__ pw, int* __restrict__ pexp,
    int* __restrict__ t2s)
{
  int offs[E_NUM];
  int cnt[E_NUM];
  {
    int o = 0;
#pragma unroll
    for (int k = 0; k < E_NUM; ++k) {
      offs[k] = o;
      cnt[k] = counts[k * CSTRIDE];
      o += (cnt[k] + 255) & ~255;
    }
    if (blockIdx.x == 0 && threadIdx.x == 0) *padTot = o;
  }
  // pad fill (blocks 0..7)
  if (blockIdx.x < E_NUM) {
    int e = blockIdx.x;
    int padded = (cnt[e] + 255) & ~255;
    for (int i = cnt[e] + threadIdx.x; i < padded; i += 256) {
      ptok[offs[e]+i] = 0; pw[offs[e]+i] = 0.0f; pexp[offs[e]+i] = e;
    }
  }
  // assign
  __shared__ int lcnt[E_NUM];
  __shared__ int base[E_NUM];
  if (threadIdx.x < E_NUM) lcnt[threadIdx.x] = 0;
  __syncthreads();
  int t = blockIdx.x * 256 + threadIdx.x;
  int e[2], rank[2];
  float w[2];
#pragma unroll
  for (int k = 0; k < 2; ++k) {
    e[k] = sel[2*t+k];
    w[k] = rw[2*t+k];
    rank[k] = atomicAdd(&lcnt[e[k]], 1);
  }
  __syncthreads();
  if (threadIdx.x < E_NUM)
    base[threadIdx.x] = atomicAdd(&cursor[threadIdx.x * CSTRIDE], lcnt[threadIdx.x]);
  __syncthreads();
#pragma unroll
  for (int k = 0; k < 2; ++k) {
    int slot = offs[e[k]] + base[e[k]] + rank[k];
    ptok[slot] = t; pw[slot] = w[k]; pexp[slot] = e[k];
    t2s[2*t+k] = slot;
  }
}

// Swizzle (HW-verified R3, conflicts=0): source chunk ((tid&7)^((tid>>3)&7))*8,
// LDS dest linear, read col ^= (lane&7)<<3.

// ======== pass A: 8-phase pipelined H = relu(X*W1^T) .* (X*W3^T) ========
// R9 config EXACTLY (measured optimum of 6 variants): 256x128 tile, 8 waves,
// 1 blk/CU, NO setprio, NO XCD swizzle.
__device__ __forceinline__ void stageA8(unsigned short* dst, const unsigned short* xb,
    const int* tokr, int kt, int half, int tid, int csw) {
  int k0 = kt * 64;
#pragma unroll
  for (int r = 0; r < 2; ++r) {
    int h = half*2 + r;
    int rl = h*64 + (tid>>3);
    load_lds16(xb + (size_t)tokr[h]*D_DIM + k0 + csw, &dst[rl*64 + (tid&7)*8]);
  }
}
__device__ __forceinline__ void stageB8(unsigned short* dst, const unsigned short* W,
    int f0, int kt, int tid, int csw) {
  int k0 = kt * 64;
#pragma unroll
  for (int r = 0; r < 2; ++r) {
    int rl = r*64 + (tid>>3);
    load_lds16(W + (size_t)(f0+rl)*D_DIM + k0 + csw, &dst[rl*64 + (tid&7)*8]);
  }
}
__device__ __forceinline__ void readA8(bf16x8 (*af)[2], const unsigned short* buf,
    int wm, int lane, int xs, int mlo) {
#pragma unroll
  for (int m = 0; m < 4; ++m)
#pragma unroll
    for (int s = 0; s < 2; ++s)
      af[m][s] = *(const bf16x8*)&buf[(wm*128 + (mlo+m)*16 + (lane&15))*64 + ((s*32 + ((lane>>4)<<3)) ^ xs)];
}
__device__ __forceinline__ void readB8(bf16x8 (*bf)[2], const unsigned short* buf,
    int wn, int lane, int xs) {
#pragma unroll
  for (int n = 0; n < 2; ++n)
#pragma unroll
    for (int s = 0; s < 2; ++s)
      bf[n][s] = *(const bf16x8*)&buf[(wn*32 + n*16 + (lane&15))*64 + ((s*32 + ((lane>>4)<<3)) ^ xs)];
}
// pass A MFMA cluster: NO setprio
__device__ __forceinline__ void mfmaq(f32x4 (*acc)[2], const bf16x8 (*af)[2], const bf16x8 (*bf)[2]) {
#pragma unroll
  for (int m = 0; m < 4; ++m)
#pragma unroll
    for (int n = 0; n < 2; ++n)
#pragma unroll
      for (int s = 0; s < 2; ++s)
        acc[m][n] = __builtin_amdgcn_mfma_f32_16x16x32_bf16(af[m][s], bf[n][s], acc[m][n], 0, 0, 0);
}

__global__ __launch_bounds__(512, 2) void ffn_h8_kernel(
    const unsigned short* __restrict__ xb, const unsigned short* __restrict__ w1b,
    const unsigned short* __restrict__ w3b, const int* __restrict__ ptok,
    const int* __restrict__ pexp, const int* __restrict__ padTot,
    unsigned short* __restrict__ H)
{
  __shared__ unsigned short As0[256*64], As1[256*64];    // 64KB
  __shared__ unsigned short B1s0[128*64], B1s1[128*64];  // 32KB
  __shared__ unsigned short B3s0[128*64], B3s1[128*64];  // 32KB
  int tm = blockIdx.x >> 4;
  int tn = blockIdx.x & 15;
  int row0 = tm * 256;
  if (row0 >= *padTot) return;
  int e  = pexp[row0];
  int f0 = tn * 128;
  const unsigned short* W1 = w1b + (size_t)e * F_DIM * D_DIM;
  const unsigned short* W3 = w3b + (size_t)e * F_DIM * D_DIM;
  int tid  = threadIdx.x;
  int lane = tid & 63;
  int wid  = tid >> 6;
  int wm = wid >> 2, wn = wid & 3;
  int xs  = (lane & 7) << 3;
  int csw = ((tid & 7) ^ ((tid >> 3) & 7)) * 8;

  int tokr[4];
#pragma unroll
  for (int h = 0; h < 4; ++h) tokr[h] = ptok[row0 + h*64 + (tid>>3)];

  f32x4 acc1[8][2] = {};
  f32x4 acc3[8][2] = {};
  bf16x8 afL[4][2], afH[4][2], b1f[2][2], b3f[2][2];

  // prologue: kt0 {B1,Alo,Ahi,B3} + kt1 {B1,Alo,Ahi}
  stageB8(B1s0, W1, f0, 0, tid, csw);
  stageA8(As0, xb, tokr, 0, 0, tid, csw);
  stageA8(As0, xb, tokr, 0, 1, tid, csw);
  stageB8(B3s0, W3, f0, 0, tid, csw);
  stageB8(B1s1, W1, f0, 1, tid, csw);
  stageA8(As1, xb, tokr, 1, 0, tid, csw);
  stageA8(As1, xb, tokr, 1, 1, tid, csw);
  VMC6();
  BAR();

  for (int i = 0; i < 4; ++i) {
    int ktB = 2*i + 1;
    int s2 = (2*i + 2 < 8) ? 2*i + 2 : 6;
    int s3 = (2*i + 3 < 8) ? 2*i + 3 : 7;
    // ---- K-tile 2i from buf0 ----
    readA8(afL, As0, wm, lane, xs, 0);
    readB8(b1f, B1s0, wn, lane, xs);
    stageB8(B3s1, W3, f0, ktB, tid, csw);
    BAR(); mfmaq(&acc1[0], afL, b1f); BAR();
    readA8(afH, As0, wm, lane, xs, 4);
    stageB8(B1s0, W1, f0, s2, tid, csw);
    BAR(); mfmaq(&acc1[4], afH, b1f); BAR();
    readB8(b3f, B3s0, wn, lane, xs);
    stageA8(As0, xb, tokr, s2, 0, tid, csw);
    BAR(); mfmaq(&acc3[0], afL, b3f); BAR();
    stageA8(As0, xb, tokr, s2, 1, tid, csw);
    VMC6();
    BAR(); mfmaq(&acc3[4], afH, b3f); BAR();
    // ---- K-tile 2i+1 from buf1 ----
    readA8(afL, As1, wm, lane, xs, 0);
    readB8(b1f, B1s1, wn, lane, xs);
    stageB8(B3s0, W3, f0, s2, tid, csw);
    BAR(); mfmaq(&acc1[0], afL, b1f); BAR();
    readA8(afH, As1, wm, lane, xs, 4);
    stageB8(B1s1, W1, f0, s3, tid, csw);
    BAR(); mfmaq(&acc1[4], afH, b1f); BAR();
    readB8(b3f, B3s1, wn, lane, xs);
    stageA8(As1, xb, tokr, s3, 0, tid, csw);
    BAR(); mfmaq(&acc3[0], afL, b3f); BAR();
    stageA8(As1, xb, tokr, s3, 1, tid, csw);
    VMC6();
    BAR(); mfmaq(&acc3[4], afH, b3f); BAR();
  }

#pragma unroll
  for (int mi = 0; mi < 8; ++mi) {
    int rbase = row0 + wm*128 + mi*16 + (lane>>4)*4;
#pragma unroll
    for (int ni = 0; ni < 2; ++ni) {
      int col = f0 + wn*32 + ni*16 + (lane & 15);
#pragma unroll
      for (int j = 0; j < 4; ++j) {
        float h = fmaxf(acc1[mi][ni][j], 0.0f) * acc3[mi][ni][j];
        H[(size_t)(rbase + j) * F_DIM + col] = f2b(h);
      }
    }
  }
}

// ======== pass B: 8-phase contrib = (H * W2^T) * row_weight (R9-verified) ========
__device__ __forceinline__ void readA_O(bf16x8 (*af)[2], const unsigned short* buf,
    int wm, int lane, int xs) {
#pragma unroll
  for (int m = 0; m < 4; ++m)
#pragma unroll
    for (int s = 0; s < 2; ++s)
      af[m][s] = *(const bf16x8*)&buf[(wm*64 + m*16 + (lane&15))*64 + ((s*32 + ((lane>>4)<<3)) ^ xs)];
}
__device__ __forceinline__ void readB_O(bf16x8* bf, const unsigned short* buf,
    int wn, int lane, int xs) {
#pragma unroll
  for (int s = 0; s < 2; ++s)
    bf[s] = *(const bf16x8*)&buf[(wn*16 + (lane&15))*64 + ((s*32 + ((lane>>4)<<3)) ^ xs)];
}
__device__ __forceinline__ void mfmaO(f32x4* acc, const bf16x8 (*af)[2], const bf16x8* bf) {
  SP1();
#pragma unroll
  for (int m = 0; m < 4; ++m)
#pragma unroll
    for (int s = 0; s < 2; ++s)
      acc[m] = __builtin_amdgcn_mfma_f32_16x16x32_bf16(af[m][s], bf[s], acc[m], 0, 0, 0);
  SP0();
}
__device__ __forceinline__ void stageA_O(unsigned short* dst, const unsigned short* H,
    int row0, int kt, int tid, int csw) {
  int k0 = kt * 64;
#pragma unroll
  for (int r = 0; r < 2; ++r) {
    int rl = r*64 + (tid>>3);
    load_lds16(H + (size_t)(row0+rl)*F_DIM + k0 + csw, &dst[rl*64 + (tid&7)*8]);
  }
}
__device__ __forceinline__ void stageB_O(unsigned short* d1, unsigned short* d3,
    const unsigned short* W2, int d0, int kt, int tid, int csw) {
  int k0 = kt * 64;
  int rl = tid >> 3;
  load_lds16(W2 + (size_t)(d0+rl)*F_DIM + k0 + csw, &d1[rl*64 + (tid&7)*8]);
  load_lds16(W2 + (size_t)(d0+64+rl)*F_DIM + k0 + csw, &d3[rl*64 + (tid&7)*8]);
}

__global__ __launch_bounds__(512, 4) void ffn_out8_kernel(
    const unsigned short* __restrict__ H, const unsigned short* __restrict__ w2b,
    const int* __restrict__ pexp, const float* __restrict__ pw,
    const int* __restrict__ padTot, unsigned short* __restrict__ contrib)
{
  __shared__ unsigned short As0[128*64], As1[128*64];    // 32KB
  __shared__ unsigned short B1s0[64*64], B1s1[64*64];    // 16KB
  __shared__ unsigned short B3s0[64*64], B3s1[64*64];    // 16KB
  int wgid = (blockIdx.x & 7) * 136 + (blockIdx.x >> 3);
  int tm = wgid >> 2;
  int tn = wgid & 3;
  int row0 = tm * 128;
  if (row0 >= *padTot) return;
  int e  = pexp[row0];
  int d0 = tn * 128;
  const unsigned short* W2 = w2b + (size_t)e * D_DIM * F_DIM;
  int tid  = threadIdx.x;
  int lane = tid & 63;
  int wid  = tid >> 6;
  int wm = wid >> 2, wn = wid & 3;
  int xs  = (lane & 7) << 3;
  int csw = ((tid & 7) ^ ((tid >> 3) & 7)) * 8;

  f32x4 acc1[4] = {};
  f32x4 acc3[4] = {};
  bf16x8 af[4][2], b1f[2], b3f[2];

  const int NK = F_DIM / 64;   // 32
  stageA_O(As0, H, row0, 0, tid, csw);
  stageB_O(B1s0, B3s0, W2, d0, 0, tid, csw);
  stageA_O(As1, H, row0, 1, tid, csw);
  VMC2();
  BAR();

  for (int i = 0; i < NK/2; ++i) {
    int k1 = 2*i + 1;
    int k2 = (2*i + 2 < NK) ? 2*i + 2 : NK - 1;
    int k3 = (2*i + 3 < NK) ? 2*i + 3 : NK - 1;
    readA_O(af, As0, wm, lane, xs);
    readB_O(b1f, B1s0, wn, lane, xs);
    readB_O(b3f, B3s0, wn, lane, xs);
    stageB_O(B1s1, B3s1, W2, d0, k1, tid, csw);
    BAR(); mfmaO(acc1, af, b1f); BAR();
    stageA_O(As0, H, row0, k2, tid, csw);
    VMC2();
    BAR(); mfmaO(acc3, af, b3f); BAR();
    readA_O(af, As1, wm, lane, xs);
    readB_O(b1f, B1s1, wn, lane, xs);
    readB_O(b3f, B3s1, wn, lane, xs);
    stageB_O(B1s0, B3s0, W2, d0, k2, tid, csw);
    BAR(); mfmaO(acc1, af, b1f); BAR();
    stageA_O(As1, H, row0, k3, tid, csw);
    VMC2();
    BAR(); mfmaO(acc3, af, b3f); BAR();
  }

#pragma unroll
  for (int m = 0; m < 4; ++m) {
    int rbase = row0 + wm*64 + m*16 + (lane>>4)*4;
    float sw[4];
#pragma unroll
    for (int j = 0; j < 4; ++j) sw[j] = pw[rbase + j];
    int colL = d0 + wn*16 + (lane & 15);
#pragma unroll
    for (int j = 0; j < 4; ++j) {
      contrib[(size_t)(rbase + j) * D_DIM + colL]      = f2b(acc1[m][j] * sw[j]);
      contrib[(size_t)(rbase + j) * D_DIM + colL + 64] = f2b(acc3[m][j] * sw[j]);
    }
  }
}

// ---------------- combine ----------------
__global__ __launch_bounds__(256) void combine_kernel(
    const unsigned short* __restrict__ contrib, const int* __restrict__ t2s,
    float* __restrict__ out)
{
  int i = blockIdx.x * 256 + threadIdx.x;
  int t = i >> 7;
  int c = (i & 127) * 4;
  int s0 = t2s[2*t], s1 = t2s[2*t+1];
  ushort4 u0 = *(const ushort4*)&contrib[(size_t)s0 * D_DIM + c];
  ushort4 u1 = *(const ushort4*)&contrib[(size_t)s1 * D_DIM + c];
  float4 o;
  o.x = b2f(u0.x) + b2f(u1.x);
  o.y = b2f(u0.y) + b2f(u1.y);
  o.z = b2f(u0.z) + b2f(u1.z);
  o.w = b2f(u0.w) + b2f(u1.w);
  *(float4*)&out[(size_t)t * D_DIM + c] = o;
}

// ---------------- workspace layout ----------------
#define OFF_SEL   ((size_t)2048)
#define OFF_RW    (OFF_SEL  + (size_t)2*T_TOK*4)
#define OFF_T2S   (OFF_RW   + (size_t)2*T_TOK*4)
#define OFF_PTOK  (OFF_T2S  + (size_t)2*T_TOK*4)
#define OFF_PW    (OFF_PTOK + (size_t)MAXR*4)
#define OFF_PEXP  (OFF_PW   + (size_t)MAXR*4)
#define OFF_XB    (OFF_PEXP + (size_t)MAXR*4)
#define OFF_W1B   (OFF_XB   + (size_t)T_TOK*D_DIM*2)
#define OFF_W3B   (OFF_W1B  + (size_t)E_NUM*F_DIM*D_DIM*2)
#define OFF_W2B   (OFF_W3B  + (size_t)E_NUM*F_DIM*D_DIM*2)
#define OFF_H     (OFF_W2B  + (size_t)E_NUM*F_DIM*D_DIM*2)
#define OFF_CONTR OFF_XB   // overlays xb+w1b (dead during pass B)

extern "C" void kernel_launch(void* const* d_in, const int* in_sizes, int n_in,
                              void* d_out, int out_size, void* d_ws, size_t ws_size,
                              hipStream_t stream) {
  const float* x  = (const float*)d_in[0];
  const float* gw = (const float*)d_in[1];
  const float* w1 = (const float*)d_in[2];
  const float* w2 = (const float*)d_in[3];
  const float* w3 = (const float*)d_in[4];
  float* out = (float*)d_out;
  char* ws = (char*)d_ws;

  int*   counts = (int*)(ws + 0);
  int*   cursor = (int*)(ws + 512);
  int*   padTot = (int*)(ws + 1056);
  int*   sel    = (int*)(ws + OFF_SEL);
  float* rw     = (float*)(ws + OFF_RW);
  int*   t2s    = (int*)(ws + OFF_T2S);
  int*   ptok   = (int*)(ws + OFF_PTOK);
  float* pw     = (float*)(ws + OFF_PW);
  int*   pexp   = (int*)(ws + OFF_PEXP);
  unsigned short* xb      = (unsigned short*)(ws + OFF_XB);
  unsigned short* w1b     = (unsigned short*)(ws + OFF_W1B);
  unsigned short* w3b     = (unsigned short*)(ws + OFF_W3B);
  unsigned short* w2b     = (unsigned short*)(ws + OFF_W2B);
  unsigned short* Hbuf    = (unsigned short*)(ws + OFF_H);
  unsigned short* contrib = (unsigned short*)(ws + OFF_CONTR);

  hipMemsetAsync(ws, 0, 2048, stream);

  prelude_kernel<<<24576 + T_TOK/4, 256, 0, stream>>>(x, gw, w1, w3, w2,
                                                      sel, rw, xb, w1b, w3b, w2b);
  hist_kernel<<<T_TOK/256, 256, 0, stream>>>(sel, counts);
  assignpad_kernel<<<T_TOK/256, 256, 0, stream>>>(sel, rw, counts, cursor, padTot,
                                                  ptok, pw, pexp, t2s);

  ffn_h8_kernel<<<(MAXR/256)*(F_DIM/128), 512, 0, stream>>>(xb, w1b, w3b, ptok, pexp, padTot, Hbuf);
  ffn_out8_kernel<<<(MAXR/128)*(D_DIM/128), 512, 0, stream>>>(Hbuf, w2b, pexp, pw, padTot, contrib);
  combine_kernel<<<(T_TOK*D_DIM/4)/256, 256, 0, stream>>>(contrib, t2s, out);

  (void)in_sizes; (void)n_in; (void)out_size; (void)ws_size;
}